// Round 1
// baseline (295.144 us; speedup 1.0000x reference)
//
#include <hip/hip_runtime.h>
#include <hip/hip_bf16.h>

// Problem dims (fixed by reference setup_inputs)
#define NQ 8
#define NK 1024
#define ND 64
#define NH 1024
#define NB 8
#define NT 8192

// ---------------- Kernel 1: build projected codebook ----------------
// P[q][k][h] = bias[q][h] + sum_d codebooks[q][k][d] * W[q][h][d]
// Bias folded in: sum_q P[q, code_q, h] == out[b,h,t] exactly.
#define KT 32
__global__ __launch_bounds__(256) void build_P(const float* __restrict__ cb,
                                               const float* __restrict__ W,
                                               const float* __restrict__ bias,
                                               float* __restrict__ P) {
    int q  = blockIdx.x / (NK / KT);
    int k0 = (blockIdx.x % (NK / KT)) * KT;
    __shared__ float cbt[KT][ND];
    int tid = threadIdx.x;
    for (int idx = tid; idx < KT * ND; idx += 256) {
        cbt[idx / ND][idx % ND] =
            cb[(size_t)q * NK * ND + (size_t)(k0 + idx / ND) * ND + (idx % ND)];
    }
    __syncthreads();
    for (int h = tid; h < NH; h += 256) {
        float4 w[ND / 4];
        const float4* wp = (const float4*)(W + (size_t)q * NH * ND + (size_t)h * ND);
#pragma unroll
        for (int i = 0; i < ND / 4; ++i) w[i] = wp[i];
        float bb = bias[q * NH + h];
        for (int k = 0; k < KT; ++k) {
            float acc = bb;
#pragma unroll
            for (int i = 0; i < ND / 4; ++i) {
                acc += cbt[k][4 * i + 0] * w[i].x + cbt[k][4 * i + 1] * w[i].y +
                       cbt[k][4 * i + 2] * w[i].z + cbt[k][4 * i + 3] * w[i].w;
            }
            P[((size_t)q * NK + (size_t)(k0 + k)) * NH + h] = acc;
        }
    }
}

// ---------------- Kernel 2: gather-sum with LDS transpose ----------------
// out[b,h,t] = sum_q P[q, codes[q,b,t], h]
// Block: 256 threads (4 waves), handles 64 consecutive t for one b.
// Loop h in chunks of 128: wave reads contiguous 512B slices of P rows
// (coalesced; code made wave-uniform via readfirstlane), accumulates,
// transposes through LDS so global writes are coalesced along t.
#define TT 64
#define HC 128
__global__ __launch_bounds__(256) void gather_sum(const int* __restrict__ codes,
                                                  const float* __restrict__ P,
                                                  float* __restrict__ out) {
    const int nt = NT / TT;  // 128
    int b  = blockIdx.x / nt;
    int t0 = (blockIdx.x % nt) * TT;
    __shared__ int   cod[NQ][TT];
    __shared__ float tile[TT][HC + 1];  // +1 pad: conflict-free column reads
    int tid = threadIdx.x;
    for (int idx = tid; idx < NQ * TT; idx += 256) {
        int q = idx >> 6, i = idx & 63;
        cod[q][i] = codes[(size_t)q * NB * NT + (size_t)b * NT + t0 + i];
    }
    __syncthreads();
    int wave = tid >> 6, lane = tid & 63;
    for (int hc = 0; hc < NH; hc += HC) {
        // compute phase: each wave owns 16 positions; lane <-> 2 h-values
        for (int i = wave * 16; i < wave * 16 + 16; ++i) {
            float accx = 0.f, accy = 0.f;
#pragma unroll
            for (int q = 0; q < NQ; ++q) {
                int c = __builtin_amdgcn_readfirstlane(cod[q][i]);  // wave-uniform
                const float2* p =
                    (const float2*)(P + ((size_t)q * NK + (size_t)c) * NH + hc);
                float2 v = p[lane];
                accx += v.x;
                accy += v.y;
            }
            tile[i][2 * lane]     = accx;
            tile[i][2 * lane + 1] = accy;
        }
        __syncthreads();
        // write phase: coalesced along t; lane <-> t, each wave 32 h-rows
        size_t ob = (size_t)b * NH * NT + (size_t)hc * NT + (size_t)t0;
#pragma unroll
        for (int r = 0; r < 32; ++r) {
            int hh = wave * 32 + r;
            out[ob + (size_t)hh * NT + lane] = tile[lane][hh];
        }
        __syncthreads();
    }
}

extern "C" void kernel_launch(void* const* d_in, const int* in_sizes, int n_in,
                              void* d_out, int out_size, void* d_ws, size_t ws_size,
                              hipStream_t stream) {
    const int*   codes = (const int*)d_in[0];    // [Q,B,T] int32
    const float* cb    = (const float*)d_in[1];  // [Q,K,D] f32
    const float* W     = (const float*)d_in[2];  // [Q,H,D] f32
    const float* bias  = (const float*)d_in[3];  // [Q,H] f32
    float*       out   = (float*)d_out;          // [B,H,T] f32
    float*       P     = (float*)d_ws;           // [Q,K,H] f32 = 33.5 MB scratch

    build_P<<<NQ * (NK / KT), 256, 0, stream>>>(cb, W, bias, P);
    gather_sum<<<NB * (NT / TT), 256, 0, stream>>>(codes, P, out);
}

// Round 2
// 235.931 us; speedup vs baseline: 1.2510x; 1.2510x over previous
//
#include <hip/hip_runtime.h>
#include <hip/hip_bf16.h>

// Problem dims (fixed by reference setup_inputs)
#define NQ 8
#define NK 1024
#define ND 64
#define NH 1024
#define NB 8
#define NT 8192

// ---------------- Kernel 1: build projected codebook ----------------
// P[q][k][h] = bias[q][h] + sum_d codebooks[q][k][d] * W[q][h][d]
#define KT 32
#define HT 256
__global__ __launch_bounds__(256) void build_P(const float* __restrict__ cb,
                                               const float* __restrict__ W,
                                               const float* __restrict__ bias,
                                               float* __restrict__ P) {
    int nkt = NK / KT;            // 32
    int nht = NH / HT;            // 4
    int q  = blockIdx.x / (nkt * nht);
    int r  = blockIdx.x % (nkt * nht);
    int k0 = (r / nht) * KT;
    int h  = (r % nht) * HT + threadIdx.x;

    __shared__ float cbt[KT][ND];
    int tid = threadIdx.x;
    // stage KT x ND codebook slice (2048 floats) via float4
    const float4* src = (const float4*)(cb + (size_t)q * NK * ND + (size_t)k0 * ND);
    float4* dst = (float4*)&cbt[0][0];
    for (int idx = tid; idx < KT * ND / 4; idx += 256) dst[idx] = src[idx];
    __syncthreads();

    float4 w[ND / 4];
    const float4* wp = (const float4*)(W + (size_t)q * NH * ND + (size_t)h * ND);
#pragma unroll
    for (int i = 0; i < ND / 4; ++i) w[i] = wp[i];
    float bb = bias[q * NH + h];

    for (int k = 0; k < KT; ++k) {
        float acc = bb;
#pragma unroll
        for (int i = 0; i < ND / 4; ++i) {
            acc += cbt[k][4 * i + 0] * w[i].x + cbt[k][4 * i + 1] * w[i].y +
                   cbt[k][4 * i + 2] * w[i].z + cbt[k][4 * i + 3] * w[i].w;
        }
        P[((size_t)q * NK + (size_t)(k0 + k)) * NH + h] = acc;
    }
}

// ---------------- Kernel 2: gather-sum with LDS transpose ----------------
// out[b,h,t] = sum_q P[q, codes[q,b,t], h]
// 512 threads (8 waves), TT=64 consecutive t per block. Each wave owns 8
// positions; its 64 (pos,q) row byte-offsets live in ONE VGPR (lane j <->
// pos=j>>3, q=j&7), fetched via readlane at compile-time lane indices in a
// fully unrolled 8x8 loop -> 64 independent scalar-based float2 gathers per
// wave per h-chunk. LDS transpose (even/odd arrays, stride 65: conflict-free
// both phases) makes global writes coalesced along t.
#define TT 64
#define HC 128
__global__ __launch_bounds__(512, 8) void gather_sum(const int* __restrict__ codes,
                                                     const float* __restrict__ P,
                                                     float* __restrict__ out) {
    const int nt = NT / TT;  // 128
    int b  = blockIdx.x / nt;
    int t0 = (blockIdx.x % nt) * TT;

    __shared__ float tileA[TT][HC / 2 + 1];  // even h-locals, stride 65
    __shared__ float tileB[TT][HC / 2 + 1];  // odd  h-locals

    int tid  = threadIdx.x;
    int wave = tid >> 6, lane = tid & 63;

    // lane j of this wave holds byte-offset of row P[q, c] for
    // pos = wave*8 + (j>>3), q = j&7.
    int posj = wave * 8 + (lane >> 3);
    int qj   = lane & 7;
    int c    = codes[(size_t)qj * (NB * NT) + (size_t)b * NT + t0 + posj];
    int voff = ((qj << 10) + c) << 12;  // ((q*NK + c) * NH) * 4 bytes

    const char* Pb = (const char*)P;

    for (int hc = 0; hc < NH; hc += HC) {
        // ---- compute phase: 64 independent gathers per wave ----
#pragma unroll 8
        for (int pos = 0; pos < 8; ++pos) {
            float accx = 0.f, accy = 0.f;
#pragma unroll 8
            for (int q = 0; q < 8; ++q) {
                int off = __builtin_amdgcn_readlane(voff, pos * 8 + q);
                const float2* p = (const float2*)(Pb + (unsigned)off + (size_t)hc * 4);
                float2 v = p[lane];
                accx += v.x;
                accy += v.y;
            }
            int i = wave * 8 + pos;           // t-local index
            tileA[i][lane] = accx;            // h-local = 2*lane
            tileB[i][lane] = accy;            // h-local = 2*lane+1
        }
        __syncthreads();
        // ---- write phase: coalesced along t; wave handles 16 h-rows ----
        size_t ob = (size_t)b * NH * NT + (size_t)hc * NT + (size_t)t0;
#pragma unroll 16
        for (int r = 0; r < 16; ++r) {
            int hh = wave * 16 + r;
            float v = (hh & 1) ? tileB[lane][hh >> 1] : tileA[lane][hh >> 1];
            out[ob + (size_t)hh * NT + lane] = v;
        }
        __syncthreads();
    }
}

extern "C" void kernel_launch(void* const* d_in, const int* in_sizes, int n_in,
                              void* d_out, int out_size, void* d_ws, size_t ws_size,
                              hipStream_t stream) {
    const int*   codes = (const int*)d_in[0];    // [Q,B,T] int32
    const float* cb    = (const float*)d_in[1];  // [Q,K,D] f32
    const float* W     = (const float*)d_in[2];  // [Q,H,D] f32
    const float* bias  = (const float*)d_in[3];  // [Q,H] f32
    float*       out   = (float*)d_out;          // [B,H,T] f32
    float*       P     = (float*)d_ws;           // [Q,K,H] f32 = 33.5 MB scratch

    build_P<<<NQ * (NK / KT) * (NH / HT), 256, 0, stream>>>(cb, W, bias, P);
    gather_sum<<<NB * (NT / TT), 512, 0, stream>>>(codes, P, out);
}

// Round 3
// 213.974 us; speedup vs baseline: 1.3793x; 1.1026x over previous
//
#include <hip/hip_runtime.h>
#include <hip/hip_bf16.h>

// Problem dims (fixed by reference setup_inputs)
#define NQ 8
#define NK 1024
#define ND 64
#define NH 1024
#define NB 8
#define NT 8192

// ---------------- Kernel 1: build projected codebook ----------------
// P[q][k][h] = bias[q][h] + sum_d codebooks[q][k][d] * W[q][h][d]
#define KT 32
#define HT 256
__global__ __launch_bounds__(256) void build_P(const float* __restrict__ cb,
                                               const float* __restrict__ W,
                                               const float* __restrict__ bias,
                                               float* __restrict__ P) {
    int nkt = NK / KT;            // 32
    int nht = NH / HT;            // 4
    int q  = blockIdx.x / (nkt * nht);
    int r  = blockIdx.x % (nkt * nht);
    int k0 = (r / nht) * KT;
    int h  = (r % nht) * HT + threadIdx.x;

    __shared__ float cbt[KT][ND];
    int tid = threadIdx.x;
    const float4* src = (const float4*)(cb + (size_t)q * NK * ND + (size_t)k0 * ND);
    float4* dst = (float4*)&cbt[0][0];
    for (int idx = tid; idx < KT * ND / 4; idx += 256) dst[idx] = src[idx];
    __syncthreads();

    float4 w[ND / 4];
    const float4* wp = (const float4*)(W + (size_t)q * NH * ND + (size_t)h * ND);
#pragma unroll
    for (int i = 0; i < ND / 4; ++i) w[i] = wp[i];
    float bb = bias[q * NH + h];

    for (int k = 0; k < KT; ++k) {
        float acc = bb;
        const float4* cv = (const float4*)&cbt[k][0];
#pragma unroll
        for (int i = 0; i < ND / 4; ++i) {
            float4 c4 = cv[i];   // ds_read_b128
            acc += c4.x * w[i].x + c4.y * w[i].y + c4.z * w[i].z + c4.w * w[i].w;
        }
        P[((size_t)q * NK + (size_t)(k0 + k)) * NH + h] = acc;
    }
}

// ---------------- Kernel 2: gather-sum, XCD-pinned h-chunks ----------------
// out[b,h,t] = sum_q P[q, codes[q,b,t], h]
// Grid = (B * T/TT) tiles x 8 h-chunks; hc = blockIdx & 7 so the round-robin
// block->XCD dispatch pins each 4 MB P chunk to exactly one XCD's L2 (fetch
// it from HBM once, serve 2.15 GB of gathers at L2 speed). Correct under any
// block->XCD permutation. 512 threads (8 waves); each wave owns 8 positions,
// its 64 (pos,q) row byte-offsets live in ONE VGPR, fetched via readlane in a
// fully unrolled 8x8 loop -> 64 independent scalar-based float2 gathers.
// LDS transpose (even/odd arrays, stride 65: conflict-free) -> writes
// coalesced along t.
#define TT 64
#define HC 128
__global__ __launch_bounds__(512, 8) void gather_sum(const int* __restrict__ codes,
                                                     const float* __restrict__ P,
                                                     float* __restrict__ out) {
    int hcIdx = blockIdx.x & 7;
    int tile  = blockIdx.x >> 3;
    int b     = tile >> 7;           // tile / (NT/TT)
    int t0    = (tile & 127) << 6;   // (tile % 128) * 64
    int hc    = hcIdx * HC;

    __shared__ float tileA[TT][HC / 2 + 1];  // even h-locals, stride 65
    __shared__ float tileB[TT][HC / 2 + 1];  // odd  h-locals

    int tid  = threadIdx.x;
    int wave = tid >> 6, lane = tid & 63;

    // lane j of this wave: byte-offset of row P[q, c] for pos=wave*8+(j>>3), q=j&7
    int posj = wave * 8 + (lane >> 3);
    int qj   = lane & 7;
    int c    = codes[(size_t)qj * (NB * NT) + (size_t)b * NT + t0 + posj];
    int voff = ((qj << 10) + c) << 12;  // ((q*NK + c) * NH) * 4 bytes

    const char* Pb = (const char*)P + (size_t)hc * 4;

    // ---- compute phase: 64 independent gathers per wave ----
#pragma unroll 8
    for (int pos = 0; pos < 8; ++pos) {
        float accx = 0.f, accy = 0.f;
#pragma unroll 8
        for (int q = 0; q < 8; ++q) {
            int off = __builtin_amdgcn_readlane(voff, pos * 8 + q);
            const float2* p = (const float2*)(Pb + (unsigned)off);
            float2 v = p[lane];
            accx += v.x;
            accy += v.y;
        }
        int i = wave * 8 + pos;  // t-local index
        tileA[i][lane] = accx;   // h-local = 2*lane
        tileB[i][lane] = accy;   // h-local = 2*lane+1
    }
    __syncthreads();
    // ---- write phase: coalesced along t; each wave handles 16 h-rows ----
    size_t ob = (size_t)b * NH * NT + (size_t)hc * NT + (size_t)t0;
#pragma unroll 16
    for (int r = 0; r < 16; ++r) {
        int hh = wave * 16 + r;
        float v = (hh & 1) ? tileB[lane][hh >> 1] : tileA[lane][hh >> 1];
        out[ob + (size_t)hh * NT + lane] = v;
    }
}

extern "C" void kernel_launch(void* const* d_in, const int* in_sizes, int n_in,
                              void* d_out, int out_size, void* d_ws, size_t ws_size,
                              hipStream_t stream) {
    const int*   codes = (const int*)d_in[0];    // [Q,B,T] int32
    const float* cb    = (const float*)d_in[1];  // [Q,K,D] f32
    const float* W     = (const float*)d_in[2];  // [Q,H,D] f32
    const float* bias  = (const float*)d_in[3];  // [Q,H] f32
    float*       out   = (float*)d_out;          // [B,H,T] f32
    float*       P     = (float*)d_ws;           // [Q,K,H] f32 = 33.5 MB scratch

    build_P<<<NQ * (NK / KT) * (NH / HT), 256, 0, stream>>>(cb, W, bias, P);
    gather_sum<<<NB * (NT / TT) * (NH / HC), 512, 0, stream>>>(codes, P, out);
}

// Round 4
// 95.976 us; speedup vs baseline: 3.0752x; 2.2295x over previous
//
#include <hip/hip_runtime.h>
#include <hip/hip_bf16.h>

// Problem dims (fixed by reference setup_inputs)
#define NQ 8
#define NK 1024
#define ND 64
#define NH 1024
#define NB 8
#define NT 8192

__device__ __forceinline__ unsigned bf16_rne(float f) {
    unsigned u = __float_as_uint(f);
    return (u + 0x7fffu + ((u >> 16) & 1u)) >> 16;
}

// ---------------- Kernel 1: build projected codebook (bf16) ----------------
// P[q][k][h] = bf16( bias[q][h] + sum_d codebooks[q][k][d] * W[q][h][d] )
#define KT 32
#define HT 256
__global__ __launch_bounds__(256) void build_P(const float* __restrict__ cb,
                                               const float* __restrict__ W,
                                               const float* __restrict__ bias,
                                               unsigned* __restrict__ P2) {  // packed 2x bf16
    int nkt = NK / KT;            // 32
    int nht = NH / HT;            // 4
    int q  = blockIdx.x / (nkt * nht);
    int r  = blockIdx.x % (nkt * nht);
    int k0 = (r / nht) * KT;
    int h  = (r % nht) * HT + threadIdx.x;

    __shared__ float cbt[KT][ND];
    int tid = threadIdx.x;
    const float4* src = (const float4*)(cb + (size_t)q * NK * ND + (size_t)k0 * ND);
    float4* dst = (float4*)&cbt[0][0];
    for (int idx = tid; idx < KT * ND / 4; idx += 256) dst[idx] = src[idx];
    __syncthreads();

    float4 w[ND / 4];
    const float4* wp = (const float4*)(W + (size_t)q * NH * ND + (size_t)h * ND);
#pragma unroll
    for (int i = 0; i < ND / 4; ++i) w[i] = wp[i];
    float bb = bias[q * NH + h];

    int lane = tid & 63;
    for (int k = 0; k < KT; ++k) {
        float acc = bb;
        const float4* cv = (const float4*)&cbt[k][0];
#pragma unroll
        for (int i = 0; i < ND / 4; ++i) {
            float4 c4 = cv[i];   // ds_read_b128
            acc += c4.x * w[i].x + c4.y * w[i].y + c4.z * w[i].z + c4.w * w[i].w;
        }
        // pack adjacent-h pair into one uint, even lane stores
        float other = __shfl_xor(acc, 1);
        if (!(lane & 1)) {
            unsigned pk = bf16_rne(acc) | (bf16_rne(other) << 16);
            P2[(((size_t)q * NK + (size_t)(k0 + k)) * NH + h) >> 1] = pk;
        }
    }
}

// ---------------- Kernel 2: gather-sum, XCD-pinned h-chunks, bf16 P --------
// out[b,h,t] = sum_q P[q, codes[q,b,t], h]
// Grid = tiles x 8 h-chunks; hc = blockIdx & 7 -> round-robin block->XCD
// dispatch pins each 2 MB bf16 P chunk to one XCD's L2 (half of L2, leaving
// headroom). Nontemporal out stores keep the 262 MB write stream from
// evicting P. Each wave owns 8 positions; 64 (pos,q) row byte-offsets in ONE
// VGPR, fetched via readlane in unrolled 8x8 loop -> 64 independent
// scalar-based uint gathers (2 bf16 h-values each). LDS transpose -> writes
// coalesced along t.
#define TT 64
#define HC 128
__global__ __launch_bounds__(512, 8) void gather_sum(const int* __restrict__ codes,
                                                     const unsigned* __restrict__ P2,
                                                     float* __restrict__ out) {
    int hcIdx = blockIdx.x & 7;
    int tile  = blockIdx.x >> 3;
    int b     = tile >> 7;           // tile / (NT/TT)
    int t0    = (tile & 127) << 6;   // (tile % 128) * 64
    int hc    = hcIdx * HC;

    __shared__ float tileA[TT][HC / 2 + 1];  // even h-locals, stride 65
    __shared__ float tileB[TT][HC / 2 + 1];  // odd  h-locals

    int tid  = threadIdx.x;
    int wave = tid >> 6, lane = tid & 63;

    // lane j of this wave: byte-offset of row P[q, c] for pos=wave*8+(j>>3), q=j&7
    int posj = wave * 8 + (lane >> 3);
    int qj   = lane & 7;
    int c    = codes[(size_t)qj * (NB * NT) + (size_t)b * NT + t0 + posj];
    int voff = ((qj << 10) + c) << 11;  // ((q*NK + c) * NH) * 2 bytes (bf16)

    const char* Pb = (const char*)P2 + (size_t)hc * 2;

    // ---- compute phase: 64 independent gathers per wave ----
#pragma unroll 8
    for (int pos = 0; pos < 8; ++pos) {
        float accx = 0.f, accy = 0.f;
#pragma unroll 8
        for (int q = 0; q < 8; ++q) {
            int off = __builtin_amdgcn_readlane(voff, pos * 8 + q);
            const unsigned* p = (const unsigned*)(Pb + (unsigned)off);
            unsigned u = p[lane];                       // 2 bf16: h-locals 2*lane, 2*lane+1
            accx += __uint_as_float(u << 16);
            accy += __uint_as_float(u & 0xffff0000u);
        }
        int i = wave * 8 + pos;  // t-local index
        tileA[i][lane] = accx;   // h-local = 2*lane
        tileB[i][lane] = accy;   // h-local = 2*lane+1
    }
    __syncthreads();
    // ---- write phase: coalesced along t; each wave handles 16 h-rows ----
    size_t ob = (size_t)b * NH * NT + (size_t)hc * NT + (size_t)t0;
#pragma unroll 16
    for (int r = 0; r < 16; ++r) {
        int hh = wave * 16 + r;
        float v = (hh & 1) ? tileB[lane][hh >> 1] : tileA[lane][hh >> 1];
        __builtin_nontemporal_store(v, &out[ob + (size_t)hh * NT + lane]);
    }
}

extern "C" void kernel_launch(void* const* d_in, const int* in_sizes, int n_in,
                              void* d_out, int out_size, void* d_ws, size_t ws_size,
                              hipStream_t stream) {
    const int*   codes = (const int*)d_in[0];    // [Q,B,T] int32
    const float* cb    = (const float*)d_in[1];  // [Q,K,D] f32
    const float* W     = (const float*)d_in[2];  // [Q,H,D] f32
    const float* bias  = (const float*)d_in[3];  // [Q,H] f32
    float*       out   = (float*)d_out;          // [B,H,T] f32
    unsigned*    P2    = (unsigned*)d_ws;        // [Q,K,H] bf16 = 16 MB scratch

    build_P<<<NQ * (NK / KT) * (NH / HT), 256, 0, stream>>>(cb, W, bias, P2);
    gather_sum<<<NB * (NT / TT) * (NH / HC), 512, 0, stream>>>(codes, P2, out);
}